// Round 1
// baseline (404.818 us; speedup 1.0000x reference)
//
#include <hip/hip_runtime.h>
#include <math.h>

#define N_SEQ 384
#define DIM 512
#define BATCH 8
#define M_ROWS (BATCH * N_SEQ)   // 3072

// ---------------------------------------------------------------------------
// Kernel 1: fused q/k projection GEMM.  C = h @ W^T (+bq for the q half).
// M=3072 rows, 1024 output cols (0..511 -> q via Wq, 512..1023 -> k via Wk).
// 64x64 tile per 256-thread block, BK=16, 4x4 microtile per thread.
// ---------------------------------------------------------------------------
__global__ __launch_bounds__(256) void qk_gemm(
    const float* __restrict__ h, const float* __restrict__ Wq,
    const float* __restrict__ bq, const float* __restrict__ Wk,
    float* __restrict__ q, float* __restrict__ k)
{
    __shared__ float As[16][65];   // [k][m], +1 pad breaks pow2 bank stride
    __shared__ float Bs[16][65];   // [k][n]
    const int bm = blockIdx.x * 64;
    const int bn = blockIdx.y * 64;          // 0..1023
    const bool is_q = (bn < DIM);
    const float* __restrict__ W = is_q ? Wq : Wk;
    const int wc0 = is_q ? bn : (bn - DIM);
    const int tid = threadIdx.x;
    const int tx = tid & 15, ty = tid >> 4;
    const int lr = tid >> 2;                 // 0..63  (tile row for loads)
    const int lc = (tid & 3) << 2;           // 0,4,8,12 (k offset for loads)
    float acc[4][4] = {};
    for (int k0 = 0; k0 < DIM; k0 += 16) {
        float4 va = *(const float4*)(h + (size_t)(bm + lr) * DIM + k0 + lc);
        float4 vb = *(const float4*)(W + (size_t)(wc0 + lr) * DIM + k0 + lc);
        __syncthreads();
        As[lc + 0][lr] = va.x; As[lc + 1][lr] = va.y;
        As[lc + 2][lr] = va.z; As[lc + 3][lr] = va.w;
        Bs[lc + 0][lr] = vb.x; Bs[lc + 1][lr] = vb.y;
        Bs[lc + 2][lr] = vb.z; Bs[lc + 3][lr] = vb.w;
        __syncthreads();
#pragma unroll
        for (int kk = 0; kk < 16; ++kk) {
            float a[4], bb[4];
#pragma unroll
            for (int u = 0; u < 4; ++u) {
                a[u]  = As[kk][ty * 4 + u];
                bb[u] = Bs[kk][tx * 4 + u];
            }
#pragma unroll
            for (int ii = 0; ii < 4; ++ii)
#pragma unroll
                for (int jj = 0; jj < 4; ++jj)
                    acc[ii][jj] = fmaf(a[ii], bb[jj], acc[ii][jj]);
        }
    }
#pragma unroll
    for (int ii = 0; ii < 4; ++ii) {
        const int row = bm + ty * 4 + ii;
#pragma unroll
        for (int jj = 0; jj < 4; ++jj) {
            const int col = bn + tx * 4 + jj;
            if (is_q) q[(size_t)row * DIM + col] = acc[ii][jj] + bq[col];
            else      k[(size_t)row * DIM + (col - DIM)] = acc[ii][jj];
        }
    }
}

// ---------------------------------------------------------------------------
// Kernel 2: left/right GEMVs. One wave per row (4 rows per 256-thread block).
// ---------------------------------------------------------------------------
__global__ __launch_bounds__(256) void lr_gemv(
    const float* __restrict__ h, const float* __restrict__ wlr,
    const float* __restrict__ blr, const float* __restrict__ wrl,
    const float* __restrict__ brl, float* __restrict__ left,
    float* __restrict__ right)
{
    const int row  = blockIdx.x * 4 + (threadIdx.x >> 6);
    const int lane = threadIdx.x & 63;
    const float* hr = h + (size_t)row * DIM;
    float sl = 0.f, sr = 0.f;
    for (int c = lane; c < DIM; c += 64) {
        const float hv = hr[c];
        sl = fmaf(hv, wlr[c], sl);
        sr = fmaf(hv, wrl[c], sr);
    }
#pragma unroll
    for (int off = 32; off > 0; off >>= 1) {
        sl += __shfl_down(sl, off);
        sr += __shfl_down(sr, off);
    }
    if (lane == 0) {
        left[row]  = sl + blr[0];
        right[row] = sr + brl[0];
    }
}

// ---------------------------------------------------------------------------
// Kernel 3: per-batch scores GEMM (q_b @ k_b^T) fused with the
// raw = clip(alpha*s + beta*d + gamma) epilogue.  raw is the only
// materialized intermediate of the attention math.
// ---------------------------------------------------------------------------
__global__ __launch_bounds__(256) void score_gemm(
    const float* __restrict__ q, const float* __restrict__ k,
    const float* __restrict__ left, const float* __restrict__ right,
    const float* __restrict__ alpha, const float* __restrict__ beta,
    const float* __restrict__ gamma, float* __restrict__ raw)
{
    __shared__ float As[16][65];
    __shared__ float Bs[16][65];
    const int b  = blockIdx.z;
    const int bi = blockIdx.x * 64;   // query rows
    const int bj = blockIdx.y * 64;   // key cols
    const float* __restrict__ qb = q + (size_t)b * N_SEQ * DIM;
    const float* __restrict__ kb = k + (size_t)b * N_SEQ * DIM;
    const int tid = threadIdx.x;
    const int tx = tid & 15, ty = tid >> 4;
    const int lr = tid >> 2;
    const int lc = (tid & 3) << 2;
    float acc[4][4] = {};
    for (int k0 = 0; k0 < DIM; k0 += 16) {
        float4 va = *(const float4*)(qb + (size_t)(bi + lr) * DIM + k0 + lc);
        float4 vb = *(const float4*)(kb + (size_t)(bj + lr) * DIM + k0 + lc);
        __syncthreads();
        As[lc + 0][lr] = va.x; As[lc + 1][lr] = va.y;
        As[lc + 2][lr] = va.z; As[lc + 3][lr] = va.w;
        Bs[lc + 0][lr] = vb.x; Bs[lc + 1][lr] = vb.y;
        Bs[lc + 2][lr] = vb.z; Bs[lc + 3][lr] = vb.w;
        __syncthreads();
#pragma unroll
        for (int kk = 0; kk < 16; ++kk) {
            float a[4], bb[4];
#pragma unroll
            for (int u = 0; u < 4; ++u) {
                a[u]  = As[kk][ty * 4 + u];
                bb[u] = Bs[kk][tx * 4 + u];
            }
#pragma unroll
            for (int ii = 0; ii < 4; ++ii)
#pragma unroll
                for (int jj = 0; jj < 4; ++jj)
                    acc[ii][jj] = fmaf(a[ii], bb[jj], acc[ii][jj]);
        }
    }
    const float al = alpha[0], be = beta[0], ga = gamma[0];
#pragma unroll
    for (int ii = 0; ii < 4; ++ii) {
        const int i = bi + ty * 4 + ii;
        const float lv = left[b * N_SEQ + i];
        const float rv = right[b * N_SEQ + i];
#pragma unroll
        for (int jj = 0; jj < 4; ++jj) {
            const int j = bj + tx * 4 + jj;
            const float dterm = (j >= i) ? lv : rv;
            float v = fmaf(al, acc[ii][jj], fmaf(be, dterm, ga));
            v = fminf(fmaxf(v, -16.f), 14.f);
            raw[((size_t)b * N_SEQ + i) * N_SEQ + j] = v;
        }
    }
}

// ---------------------------------------------------------------------------
// Kernel 4: per (b,i) row finalize.  Recomputes log_p / log_1mp from raw,
// prefix-scans log_1mp, then evaluates the two analytic mask intervals:
//   i<j: (P[j]-P[i+1]) + (P[i]-P[max(2i-j+1,0)])
//   i>j: (P[i]-P[j+1]) + (P[min(2i-j+1,N)]-P[i+1])
// Also writes alignment_mask = mask[b,i]*mask[b,j].
// ---------------------------------------------------------------------------
__global__ __launch_bounds__(384) void finalize(
    const float* __restrict__ raw, const float* __restrict__ mask,
    float* __restrict__ out_r, float* __restrict__ out_am)
{
    const int n = N_SEQ;
    const int i = blockIdx.x;
    const int b = blockIdx.y;
    const int j = threadIdx.x;     // 0..383
    __shared__ float P[N_SEQ + 1];
    __shared__ float wsum[6];
    const float x  = raw[((size_t)b * n + i) * n + j];
    const float lp = -log1pf(expf(-x));   // log sigmoid(x)
    const float l1 = -log1pf(expf(x));    // log(1 - sigmoid(x))
    const int lane = j & 63, w = j >> 6;
    float v = l1;
#pragma unroll
    for (int off = 1; off < 64; off <<= 1) {
        const float t = __shfl_up(v, off);
        if (lane >= off) v += t;
    }
    if (lane == 63) wsum[w] = v;
    __syncthreads();
    float woff = 0.f;
    for (int t = 0; t < w; ++t) woff += wsum[t];
    P[j + 1] = v + woff;               // inclusive scan -> exclusive P
    if (j == 0) P[0] = 0.f;
    __syncthreads();
    float s = 0.f;
    if (i < j) {
        int lo2 = 2 * i - j + 1; if (lo2 < 0) lo2 = 0;
        s = (P[j] - P[i + 1]) + (P[i] - P[lo2]);
    } else if (i > j) {
        int hi2 = 2 * i - j + 1; if (hi2 > n) hi2 = n;
        s = (P[i] - P[j + 1]) + (P[hi2] - P[i + 1]);
    }
    float r = s + lp;
    if (i == j) r -= 10000.f;
    const size_t o = ((size_t)b * n + i) * n + j;
    out_r[o]  = r;
    out_am[o] = mask[b * n + i] * mask[b * n + j];
}

// ---------------------------------------------------------------------------
extern "C" void kernel_launch(void* const* d_in, const int* in_sizes, int n_in,
                              void* d_out, int out_size, void* d_ws, size_t ws_size,
                              hipStream_t stream) {
    const float* h     = (const float*)d_in[0];
    const float* mask  = (const float*)d_in[1];
    const float* Wq    = (const float*)d_in[2];
    const float* bq    = (const float*)d_in[3];
    const float* Wk    = (const float*)d_in[4];
    const float* wlr   = (const float*)d_in[5];
    const float* blr   = (const float*)d_in[6];
    const float* wrl   = (const float*)d_in[7];
    const float* brl   = (const float*)d_in[8];
    const float* alpha = (const float*)d_in[9];
    const float* beta  = (const float*)d_in[10];
    const float* gamma = (const float*)d_in[11];
    // d_in[12] (masking_matrix, 384^3 bool) intentionally unused: the mask is
    // two analytic contiguous k-intervals -> prefix-sum trick in finalize().

    float* ws    = (float*)d_ws;
    float* q     = ws;                          // 3072*512
    float* k     = q + (size_t)M_ROWS * DIM;    // 3072*512
    float* left  = k + (size_t)M_ROWS * DIM;    // 3072
    float* right = left + M_ROWS;               // 3072
    float* raw   = right + M_ROWS;              // 8*384*384

    float* out_r  = (float*)d_out;
    float* out_am = out_r + (size_t)BATCH * N_SEQ * N_SEQ;

    dim3 g1(M_ROWS / 64, (2 * DIM) / 64);       // 48 x 16
    qk_gemm<<<g1, 256, 0, stream>>>(h, Wq, bq, Wk, q, k);
    lr_gemv<<<M_ROWS / 4, 256, 0, stream>>>(h, wlr, blr, wrl, brl, left, right);
    dim3 g2(N_SEQ / 64, N_SEQ / 64, BATCH);     // 6 x 6 x 8
    score_gemm<<<g2, 256, 0, stream>>>(q, k, left, right, alpha, beta, gamma, raw);
    dim3 g3(N_SEQ, BATCH);
    finalize<<<g3, 384, 0, stream>>>(raw, mask, out_r, out_am);
}

// Round 2
// 316.836 us; speedup vs baseline: 1.2777x; 1.2777x over previous
//
#include <hip/hip_runtime.h>
#include <math.h>

#define N_SEQ 384
#define DIM 512
#define BATCH 8
#define M_ROWS (BATCH * N_SEQ)   // 3072
#define QK_COLS (2 * DIM)        // 1024: cols 0..511 = q, 512..1023 = k

typedef short v8s __attribute__((ext_vector_type(8)));   // 8 bf16 (4 VGPRs)
typedef float v4f __attribute__((ext_vector_type(4)));   // MFMA f32 acc

__device__ inline unsigned short f2bf(float f) {
    union { float f; unsigned u; } c; c.f = f;
    unsigned u = c.u;
    u += 0x7fffu + ((u >> 16) & 1u);   // RNE (inputs finite)
    return (unsigned short)(u >> 16);
}

// ---------------------------------------------------------------------------
// Kernel 0: cast h / Wq / Wk (fp32) -> bf16 workspace buffers.
// One float4 per thread over the concatenated range.
// ---------------------------------------------------------------------------
#define H_F4   ((M_ROWS * DIM) / 4)          // 393216
#define W_F4   ((DIM * DIM) / 4)             // 65536
__global__ __launch_bounds__(256) void cast_inputs(
    const float* __restrict__ h, const float* __restrict__ Wq,
    const float* __restrict__ Wk, unsigned short* __restrict__ h_bf,
    unsigned short* __restrict__ w_bf)
{
    const int idx = blockIdx.x * 256 + threadIdx.x;
    const float4* src; unsigned short* dst; int off;
    if (idx < H_F4)            { src = (const float4*)h;  dst = h_bf;            off = idx; }
    else if (idx < H_F4 + W_F4){ src = (const float4*)Wq; dst = w_bf;            off = idx - H_F4; }
    else                       { src = (const float4*)Wk; dst = w_bf + DIM * DIM/ sizeof(short) * 2; off = idx - H_F4 - W_F4; }
    // note: w_bf + DIM*DIM elements for the Wk half
    if (idx >= H_F4 + W_F4) dst = w_bf + (size_t)DIM * DIM;  // fix offset cleanly
    float4 v = src[off];
    ushort4 o;
    o.x = f2bf(v.x); o.y = f2bf(v.y); o.z = f2bf(v.z); o.w = f2bf(v.w);
    *(ushort4*)(dst + (size_t)off * 4) = o;
}

// ---------------------------------------------------------------------------
// Kernel 1: MFMA qk projection.  C[3072x1024] = h_bf @ [Wq;Wk]^T (+bq on q half),
// stored bf16.  128x128 tile, 4 waves, each wave 64x64 = 4x4 of 16x16x32.
// LDS K-stride padded to 40 bf16 (80 B): bank stride 20 -> 2-way (free).
// ---------------------------------------------------------------------------
__global__ __launch_bounds__(256) void qk_gemm(
    const unsigned short* __restrict__ A,   // h_bf 3072x512
    const unsigned short* __restrict__ Bm,  // w_bf 1024x512
    const float* __restrict__ bq,
    unsigned short* __restrict__ C)         // qk_bf 3072x1024
{
    __shared__ unsigned short As[128][40];
    __shared__ unsigned short Bs[128][40];
    const int bm = blockIdx.x * 128;
    const int bn = blockIdx.y * 128;
    const int t = threadIdx.x;
    const int wv = t >> 6, lane = t & 63;
    const int wm = (wv & 1) * 64, wn = (wv >> 1) * 64;
    const int lm = lane & 15, quad = lane >> 4;
    const int srow = t >> 2, skc = (t & 3) * 8;
    v4f acc[4][4] = {};
    for (int k0 = 0; k0 < DIM; k0 += 32) {
        v8s a0 = *(const v8s*)(A  + (size_t)(bm + srow)      * DIM + k0 + skc);
        v8s a1 = *(const v8s*)(A  + (size_t)(bm + srow + 64) * DIM + k0 + skc);
        v8s b0 = *(const v8s*)(Bm + (size_t)(bn + srow)      * DIM + k0 + skc);
        v8s b1 = *(const v8s*)(Bm + (size_t)(bn + srow + 64) * DIM + k0 + skc);
        __syncthreads();
        *(v8s*)&As[srow][skc]      = a0;
        *(v8s*)&As[srow + 64][skc] = a1;
        *(v8s*)&Bs[srow][skc]      = b0;
        *(v8s*)&Bs[srow + 64][skc] = b1;
        __syncthreads();
        v8s af[4], bf[4];
#pragma unroll
        for (int i = 0; i < 4; ++i) af[i] = *(const v8s*)&As[wm + i * 16 + lm][quad * 8];
#pragma unroll
        for (int j = 0; j < 4; ++j) bf[j] = *(const v8s*)&Bs[wn + j * 16 + lm][quad * 8];
#pragma unroll
        for (int i = 0; i < 4; ++i)
#pragma unroll
            for (int j = 0; j < 4; ++j)
                acc[i][j] = __builtin_amdgcn_mfma_f32_16x16x32_bf16(af[i], bf[j], acc[i][j], 0, 0, 0);
    }
#pragma unroll
    for (int i = 0; i < 4; ++i)
#pragma unroll
        for (int j = 0; j < 4; ++j) {
            const int col = bn + wn + j * 16 + lm;
            const float bias = (col < DIM) ? bq[col] : 0.f;
#pragma unroll
            for (int r = 0; r < 4; ++r) {
                const int row = bm + wm + i * 16 + quad * 4 + r;
                C[(size_t)row * QK_COLS + col] = f2bf(acc[i][j][r] + bias);
            }
        }
}

// ---------------------------------------------------------------------------
// Kernel 2: left/right GEMVs (fp32, reads original h). One wave per row.
// ---------------------------------------------------------------------------
__global__ __launch_bounds__(256) void lr_gemv(
    const float* __restrict__ h, const float* __restrict__ wlr,
    const float* __restrict__ blr, const float* __restrict__ wrl,
    const float* __restrict__ brl, float* __restrict__ left,
    float* __restrict__ right)
{
    const int row  = blockIdx.x * 4 + (threadIdx.x >> 6);
    const int lane = threadIdx.x & 63;
    const float* hr = h + (size_t)row * DIM;
    float sl = 0.f, sr = 0.f;
    for (int c = lane; c < DIM; c += 64) {
        const float hv = hr[c];
        sl = fmaf(hv, wlr[c], sl);
        sr = fmaf(hv, wrl[c], sr);
    }
#pragma unroll
    for (int off = 32; off > 0; off >>= 1) {
        sl += __shfl_down(sl, off);
        sr += __shfl_down(sr, off);
    }
    if (lane == 0) {
        left[row]  = sl + blr[0];
        right[row] = sr + brl[0];
    }
}

// ---------------------------------------------------------------------------
// Kernel 3: MFMA batched scores q_b @ k_b^T fused with
// raw = clip(alpha*s + beta*d + gamma).  64x64 tile, 4 waves, each 32x32.
// ---------------------------------------------------------------------------
__global__ __launch_bounds__(256) void score_gemm(
    const unsigned short* __restrict__ QK, const float* __restrict__ left,
    const float* __restrict__ right, const float* __restrict__ alpha,
    const float* __restrict__ beta, const float* __restrict__ gamma,
    float* __restrict__ raw)
{
    __shared__ unsigned short As[64][40];
    __shared__ unsigned short Bs[64][40];
    const int b  = blockIdx.z;
    const int bi = blockIdx.x * 64, bj = blockIdx.y * 64;
    const int t = threadIdx.x;
    const int wv = t >> 6, lane = t & 63;
    const int wm = (wv & 1) * 32, wn = (wv >> 1) * 32;
    const int lm = lane & 15, quad = lane >> 4;
    const int srow = t >> 2, skc = (t & 3) * 8;
    const unsigned short* qb = QK + (size_t)(b * N_SEQ) * QK_COLS;
    v4f acc[2][2] = {};
    for (int k0 = 0; k0 < DIM; k0 += 32) {
        v8s a0 = *(const v8s*)(qb + (size_t)(bi + srow) * QK_COLS + k0 + skc);
        v8s b0 = *(const v8s*)(qb + (size_t)(bj + srow) * QK_COLS + DIM + k0 + skc);
        __syncthreads();
        *(v8s*)&As[srow][skc] = a0;
        *(v8s*)&Bs[srow][skc] = b0;
        __syncthreads();
        v8s af[2], bf[2];
#pragma unroll
        for (int i = 0; i < 2; ++i) af[i] = *(const v8s*)&As[wm + i * 16 + lm][quad * 8];
#pragma unroll
        for (int j = 0; j < 2; ++j) bf[j] = *(const v8s*)&Bs[wn + j * 16 + lm][quad * 8];
#pragma unroll
        for (int i = 0; i < 2; ++i)
#pragma unroll
            for (int j = 0; j < 2; ++j)
                acc[i][j] = __builtin_amdgcn_mfma_f32_16x16x32_bf16(af[i], bf[j], acc[i][j], 0, 0, 0);
    }
    const float al = alpha[0], be = beta[0], ga = gamma[0];
#pragma unroll
    for (int i = 0; i < 2; ++i)
#pragma unroll
        for (int j = 0; j < 2; ++j) {
            const int jcol = bj + wn + j * 16 + lm;
#pragma unroll
            for (int r = 0; r < 4; ++r) {
                const int irow = bi + wm + i * 16 + quad * 4 + r;
                const float lv = left[b * N_SEQ + irow];
                const float rv = right[b * N_SEQ + irow];
                const float dterm = (jcol >= irow) ? lv : rv;
                float v = fmaf(al, acc[i][j][r], fmaf(be, dterm, ga));
                v = fminf(fmaxf(v, -16.f), 14.f);
                raw[((size_t)b * N_SEQ + irow) * N_SEQ + jcol] = v;
            }
        }
}

// ---------------------------------------------------------------------------
// Kernel 4: per (b,i) row finalize (prefix-sum trick over analytic mask
// intervals; masking_matrix input never touched).
// ---------------------------------------------------------------------------
__global__ __launch_bounds__(384) void finalize(
    const float* __restrict__ raw, const float* __restrict__ mask,
    float* __restrict__ out_r, float* __restrict__ out_am)
{
    const int n = N_SEQ;
    const int i = blockIdx.x;
    const int b = blockIdx.y;
    const int j = threadIdx.x;     // 0..383
    __shared__ float P[N_SEQ + 1];
    __shared__ float wsum[6];
    const float x  = raw[((size_t)b * n + i) * n + j];
    const float lp = -log1pf(expf(-x));   // log sigmoid(x)
    const float l1 = -log1pf(expf(x));    // log(1 - sigmoid(x))
    const int lane = j & 63, w = j >> 6;
    float v = l1;
#pragma unroll
    for (int off = 1; off < 64; off <<= 1) {
        const float tt = __shfl_up(v, off);
        if (lane >= off) v += tt;
    }
    if (lane == 63) wsum[w] = v;
    __syncthreads();
    float woff = 0.f;
    for (int t = 0; t < w; ++t) woff += wsum[t];
    P[j + 1] = v + woff;
    if (j == 0) P[0] = 0.f;
    __syncthreads();
    float s = 0.f;
    if (i < j) {
        int lo2 = 2 * i - j + 1; if (lo2 < 0) lo2 = 0;
        s = (P[j] - P[i + 1]) + (P[i] - P[lo2]);
    } else if (i > j) {
        int hi2 = 2 * i - j + 1; if (hi2 > n) hi2 = n;
        s = (P[i] - P[j + 1]) + (P[hi2] - P[i + 1]);
    }
    float r = s + lp;
    if (i == j) r -= 10000.f;
    const size_t o = ((size_t)b * n + i) * n + j;
    out_r[o]  = r;
    out_am[o] = mask[b * n + i] * mask[b * n + j];
}

// ---------------------------------------------------------------------------
extern "C" void kernel_launch(void* const* d_in, const int* in_sizes, int n_in,
                              void* d_out, int out_size, void* d_ws, size_t ws_size,
                              hipStream_t stream) {
    const float* h     = (const float*)d_in[0];
    const float* mask  = (const float*)d_in[1];
    const float* Wq    = (const float*)d_in[2];
    const float* bq    = (const float*)d_in[3];
    const float* Wk    = (const float*)d_in[4];
    const float* wlr   = (const float*)d_in[5];
    const float* blr   = (const float*)d_in[6];
    const float* wrl   = (const float*)d_in[7];
    const float* brl   = (const float*)d_in[8];
    const float* alpha = (const float*)d_in[9];
    const float* beta  = (const float*)d_in[10];
    const float* gamma = (const float*)d_in[11];
    // d_in[12] (masking_matrix) intentionally unused.

    unsigned short* h_bf  = (unsigned short*)d_ws;                 // 3072*512
    unsigned short* w_bf  = h_bf + (size_t)M_ROWS * DIM;           // 1024*512
    unsigned short* qk_bf = w_bf + (size_t)QK_COLS * DIM;          // 3072*1024
    float* left  = (float*)(qk_bf + (size_t)M_ROWS * QK_COLS);     // 3072
    float* right = left + M_ROWS;                                  // 3072
    float* raw   = right + M_ROWS;                                 // 8*384*384

    float* out_r  = (float*)d_out;
    float* out_am = out_r + (size_t)BATCH * N_SEQ * N_SEQ;

    cast_inputs<<<(H_F4 + 2 * W_F4) / 256, 256, 0, stream>>>(h, Wq, Wk, h_bf, w_bf);
    lr_gemv<<<M_ROWS / 4, 256, 0, stream>>>(h, wlr, blr, wrl, brl, left, right);
    dim3 g1(M_ROWS / 128, QK_COLS / 128);       // 24 x 8
    qk_gemm<<<g1, 256, 0, stream>>>(h_bf, w_bf, bq, qk_bf);
    dim3 g2(N_SEQ / 64, N_SEQ / 64, BATCH);     // 6 x 6 x 8
    score_gemm<<<g2, 256, 0, stream>>>(qk_bf, left, right, alpha, beta, gamma, raw);
    dim3 g3(N_SEQ, BATCH);
    finalize<<<g3, 384, 0, stream>>>(raw, mask, out_r, out_am);
}